// Round 1
// baseline (412.715 us; speedup 1.0000x reference)
//
#include <hip/hip_runtime.h>
#include <math.h>

// FlowLayer: 2 steps of manifold (S^2) graph heat flow.
// N=50000 nodes, C=16 channels, D=3, E=1.6M edges.
//
// R18 = R17 +
//  - flowp software pipeline: pair entries prefetched 2 iters ahead, q
//    gathers issued 1 iter ahead. Over-reads are safe: pair has a zeroed
//    +64-entry slack and every pair entry (incl. pads) holds an in-bounds
//    rcv*48, so speculative gathers never fault and garbage w is unused.
//  - boff stored as uchar (values <= max degree ~80 << 255); scanCD's
//    "+= rs into boff" pass dropped -- fill gathers row_start[snd]
//    (200KB, L2-resident) instead. Region kept at int size so the xtmp
//    alias is unchanged.
// Build (no global atomics): LDS-privatized histogram -> fused scan1A ->
// scanCD (row_start only) -> atomic-free fill packing (w fp32, rcv*48).
//
// NOTE: |u|^2 MUST be computed from u's components (not 1-cs^2): near
// antipodal pairs 1-cs^2 cancels catastrophically -> rsq explodes (R5 bug).

constexpr float EPS64F = 2.2204460492503131e-16f;  // np.float64 eps
constexpr float PI_F   = 3.14159265358979323846f;
constexpr int   SR_BITS = 14;                 // 16384-node subranges (64KB LDS)
constexpr int   CH_BITS = 15;                 // 32768-edge chunks

typedef int   vi4 __attribute__((ext_vector_type(4)));
typedef float vf4 __attribute__((ext_vector_type(4)));
typedef float vf2 __attribute__((ext_vector_type(2)));

// ---------------- CSR build ----------------

// LDS histogram: block (c = blockIdx.x, s = blockIdx.y).
__global__ __launch_bounds__(256) void lhist_kernel(
    const int* __restrict__ snd, unsigned char* __restrict__ pos,
    unsigned char* __restrict__ partial2, int E, int NC) {
  __shared__ int h[1 << SR_BITS];
  int tid = threadIdx.x;
  int c = blockIdx.x, s = blockIdx.y;
  for (int i = tid; i < (1 << SR_BITS); i += 256) h[i] = 0;
  __syncthreads();
  int base = c << CH_BITS;
  int cnt = min(1 << CH_BITS, E - base);
  int s0 = s << SR_BITS;
  const vi4* snd4 = (const vi4*)(snd + base);  // base is 32768-aligned
  int cnt4 = cnt >> 2;
  for (int i = tid; i < cnt4; i += 256) {
    vi4 sv = snd4[i];
    int e = base + (i << 2);
    int v;
    v = sv.x - s0; if ((unsigned)v < (1u << SR_BITS)) pos[e]     = (unsigned char)atomicAdd(&h[v], 1);
    v = sv.y - s0; if ((unsigned)v < (1u << SR_BITS)) pos[e + 1] = (unsigned char)atomicAdd(&h[v], 1);
    v = sv.z - s0; if ((unsigned)v < (1u << SR_BITS)) pos[e + 2] = (unsigned char)atomicAdd(&h[v], 1);
    v = sv.w - s0; if ((unsigned)v < (1u << SR_BITS)) pos[e + 3] = (unsigned char)atomicAdd(&h[v], 1);
  }
  if (tid == 0) {  // chunk tail (cnt % 4)
    for (int i = cnt4 << 2; i < cnt; ++i) {
      int v = snd[base + i] - s0;
      if ((unsigned)v < (1u << SR_BITS))
        pos[base + i] = (unsigned char)atomicAdd(&h[v], 1);
    }
  }
  __syncthreads();
  unsigned char* dst = partial2 + ((size_t)(s * NC + c) << SR_BITS);
  for (int i = tid; i < (1 << SR_BITS); i += 256)
    dst[i] = (unsigned char)h[i];
}

// Fused scan1+scanA with row padding: per-node exclusive fold over chunks
// (boffL in place, unpadded, uchar) -> degree; tile shfl-scan of PADDED
// degree (round up to 16) -> tile-local exclusive row_start + tile totals.
__global__ __launch_bounds__(1024) void scan1A_kernel(
    const unsigned char* __restrict__ partial2, unsigned char* __restrict__ boffL,
    int* __restrict__ row_start, int* __restrict__ btot, int N, int NC) {
  __shared__ int wsum[16];
  int tid = threadIdx.x;
  int lane = tid & 63, wave = tid >> 6;
  int i = blockIdx.x * 1024 + tid;
  int vpad = 0;
  if (i < N) {
    int s = i >> SR_BITS, lv = i & ((1 << SR_BITS) - 1);
    int run = 0;
    for (int c = 0; c < NC; ++c) {
      int t = partial2[((size_t)(s * NC + c) << SR_BITS) + lv];
      boffL[(size_t)c * N + i] = (unsigned char)run;  // run <= degree <= ~80
      run += t;
    }
    vpad = (run + 15) & ~15;  // padded degree
  }
  int incl = vpad;
  #pragma unroll
  for (int off = 1; off < 64; off <<= 1) {
    int t = __shfl_up(incl, off, 64);
    if (lane >= off) incl += t;
  }
  if (lane == 63) wsum[wave] = incl;
  __syncthreads();
  if (wave == 0 && lane < 16) {
    int wincl = wsum[lane];
    #pragma unroll
    for (int off = 1; off < 16; off <<= 1) {
      int t = __shfl_up(wincl, off, 64);
      if (lane >= off) wincl += t;
    }
    wsum[lane] = wincl;
  }
  __syncthreads();
  int woff = (wave > 0) ? wsum[wave - 1] : 0;
  if (i < N) row_start[i] = woff + incl - vpad;  // tile-local exclusive
  if (tid == 0) btot[blockIdx.x] = wsum[15];
}

// scanCD (+ folded scanB): each block wave-scans the <=64 tile totals in
// LDS, then finalizes row_start only (fill adds rs via gather itself).
__global__ __launch_bounds__(256) void scanCD_kernel(
    int* __restrict__ row_start, const int* __restrict__ btot, int N, int nb) {
  __shared__ int bsh[64];
  int tid = threadIdx.x;
  if (tid < 64) {
    int v = (tid < nb) ? btot[tid] : 0;
    int incl = v;
    #pragma unroll
    for (int off = 1; off < 64; off <<= 1) {
      int t = __shfl_up(incl, off, 64);
      if (tid >= off) incl += t;
    }
    bsh[tid] = incl - v;  // exclusive tile offset
    if (blockIdx.x == 0 && tid == 63) row_start[N] = incl;  // padded total
  }
  __syncthreads();
  int i = blockIdx.x * 256 + tid;
  if (i >= N) return;
  row_start[i] = row_start[i] + bsh[i >> 10];
}

// Atomic-free fill: slot = row_start[snd] + boffL[chunk][snd] + pos[e];
// packs (w, rcv*48). Pad slots (row tails) stay zero from the memset.
// row_start (200KB) and the chunk's boffL slice (50KB) are L2-resident.
__global__ __launch_bounds__(256) void fill_kernel(
    const vi4* __restrict__ snd4, const vi4* __restrict__ rcv4,
    const vf4* __restrict__ ew4, const unsigned char* __restrict__ pos,
    const unsigned char* __restrict__ boffL, const int* __restrict__ row_start,
    long long* __restrict__ pair,
    const int* __restrict__ snd, const int* __restrict__ rcv,
    const float* __restrict__ ew, int N, int E) {
  int tid = threadIdx.x;
  int E4 = E >> 2;
  #pragma unroll
  for (int gg = 0; gg < 2; ++gg) {
    int g = blockIdx.x * 512 + gg * 256 + tid;
    if (g < E4) {
      int e = g << 2;
      const unsigned char* bc = boffL + (size_t)(e >> CH_BITS) * N;  // same chunk e..e+3
      vi4 s = __builtin_nontemporal_load(&snd4[g]);
      vi4 r = __builtin_nontemporal_load(&rcv4[g]);
      vf4 w = __builtin_nontemporal_load(&ew4[g]);
      unsigned pb = *(const unsigned*)(pos + e);
      int rs0 = row_start[s.x] + bc[s.x];
      int rs1 = row_start[s.y] + bc[s.y];
      int rs2 = row_start[s.z] + bc[s.z];
      int rs3 = row_start[s.w] + bc[s.w];
      pair[rs0 + (pb & 255u)] =
          (long long)(((unsigned long long)(unsigned)__float_as_int(w.x) << 32) | (unsigned)(r.x * 48));
      pair[rs1 + ((pb >> 8) & 255u)] =
          (long long)(((unsigned long long)(unsigned)__float_as_int(w.y) << 32) | (unsigned)(r.y * 48));
      pair[rs2 + ((pb >> 16) & 255u)] =
          (long long)(((unsigned long long)(unsigned)__float_as_int(w.z) << 32) | (unsigned)(r.z * 48));
      pair[rs3 + (pb >> 24)] =
          (long long)(((unsigned long long)(unsigned)__float_as_int(w.w) << 32) | (unsigned)(r.w * 48));
    }
  }
  if (blockIdx.x == 0 && tid == 0) {
    for (int e = E4 << 2; e < E; ++e) {  // edge tail
      int sn = snd[e];
      pair[row_start[sn] + boffL[(size_t)(e >> CH_BITS) * N + sn] + pos[e]] =
          (long long)(((unsigned long long)(unsigned)__float_as_int(ew[e]) << 32) | (unsigned)(rcv[e] * 48));
    }
  }
}

// ---------------- flow (R10 flowp math, R18 software pipeline) ----------------

__device__ __forceinline__ void edge_accum_pk(
    vf2 p0, vf2 p1, vf2 p2, vf2 q0, vf2 q1, vf2 q2, vf2 w,
    vf2& a0, vf2& a1, vf2& a2) {
  vf2 cs = p0 * q0 + p1 * q1 + p2 * q2;
  cs = __builtin_elementwise_min(vf2{1.f, 1.f},
       __builtin_elementwise_max(vf2{-1.f, -1.f}, cs));
  vf2 u0 = q0 - cs * p0;
  vf2 u1 = q1 - cs * p1;
  vf2 u2 = q2 - cs * p2;
  // |u|^2 from components (R5 lesson)
  vf2 un2 = __builtin_elementwise_max(u0 * u0 + u1 * u1 + u2 * u2,
                                      vf2{1e-24f, 1e-24f});
  // acos via A&S 4.4.45 (|err| <= 6.7e-5; output threshold is 2e-2)
  vf2 ax = __builtin_elementwise_abs(cs);
  vf2 s = __builtin_elementwise_sqrt(vf2{1.f, 1.f} - ax);
  vf2 poly = ((ax * -0.0187293f + 0.0742610f) * ax - 0.2121144f) * ax
             + 1.5707288f;
  vf2 th = s * poly;
  vf2 theta;
  theta.x = (cs.x >= 0.0f) ? th.x : (PI_F - th.x);
  theta.y = (cs.y >= 0.0f) ? th.y : (PI_F - th.y);
  vf2 rsq;
  rsq.x = __builtin_amdgcn_rsqf(un2.x);
  rsq.y = __builtin_amdgcn_rsqf(un2.y);
  vf2 coef = w * theta * rsq;
  a0 += coef * u0;
  a1 += coef * u1;
  a2 += coef * u2;
}

__device__ __forceinline__ void node_step(
    float a0, float a1, float a2, float ws, float p0, float p1, float p2,
    float ts, float dsv, float& y0, float& y1, float& y2) {
  // v_lap = -agg/deg; nrm/scale sign-invariant; -(v_lap*scale)*t = +g*scale*t
  float invdg = __builtin_amdgcn_rcpf(ws + 1e-12f);
  float g0 = a0 * invdg, g1 = a1 * invdg, g2 = a2 * invdg;
  float nrm = sqrtf(fmaf(g0, g0, fmaf(g1, g1, g2 * g2)) + EPS64F);
  float tch = ts * ts * 0.5f;  // t_sqrt^2 / N_STEPS
  float dch = dsv * dsv;
  float alp = __builtin_amdgcn_rcpf(1.0f + __expf(dch - nrm));  // sigmoid
  float scale = (nrm * alp <= 1.0f) ? alp : __builtin_amdgcn_rcpf(nrm);
  float f = scale * tch;
  float v0 = g0 * f, v1 = g1 * f, v2 = g2 * f;
  float nv = sqrtf(fmaf(v0, v0, fmaf(v1, v1, v2 * v2)));
  float cn = __cosf(nv);
  float sc = (nv > 1e-20f) ? (__sinf(nv) * __builtin_amdgcn_rcpf(nv)) : 1.0f;
  float t0 = fmaf(cn, p0, sc * v0);
  float t1 = fmaf(cn, p1, sc * v1);
  float t2 = fmaf(cn, p2, sc * v2);
  float inv = __builtin_amdgcn_rsqf(fmaf(t0, t0, fmaf(t1, t1, t2 * t2)));
  y0 = t0 * inv; y1 = t1 * inv; y2 = t2 * inv;
}

struct EQ { long long e0, e1, e2, e3; };
struct Q4 { float a0, a1, a2, b0, b1, b2, c0, c1, c2, d0, d1, d2; };

__device__ __forceinline__ EQ load_e(const long long* __restrict__ pair, int j) {
  EQ r;
  r.e0 = __builtin_nontemporal_load(&pair[j]);
  r.e1 = __builtin_nontemporal_load(&pair[j + 4]);
  r.e2 = __builtin_nontemporal_load(&pair[j + 8]);
  r.e3 = __builtin_nontemporal_load(&pair[j + 12]);
  return r;
}

__device__ __forceinline__ Q4 load_q(const float* __restrict__ xin, EQ e, int c3) {
  Q4 q;
  const float* q0p = xin + ((int)e.e0 + c3);
  const float* q1p = xin + ((int)e.e1 + c3);
  const float* q2p = xin + ((int)e.e2 + c3);
  const float* q3p = xin + ((int)e.e3 + c3);
  q.a0 = q0p[0]; q.a1 = q0p[1]; q.a2 = q0p[2];
  q.b0 = q1p[0]; q.b1 = q1p[1]; q.b2 = q1p[2];
  q.c0 = q2p[0]; q.c1 = q2p[1]; q.c2 = q2p[2];
  q.d0 = q3p[0]; q.d1 = q3p[1]; q.d2 = q3p[2];
  return q;
}

__device__ __forceinline__ void compute_iter(
    EQ e, const Q4& q, vf2 p0, vf2 p1, vf2 p2,
    vf2& a0, vf2& a1, vf2& a2, vf2& wsv) {
  float w0 = __int_as_float((int)(e.e0 >> 32));
  float w1 = __int_as_float((int)(e.e1 >> 32));
  float w2 = __int_as_float((int)(e.e2 >> 32));
  float w3 = __int_as_float((int)(e.e3 >> 32));
  vf2 wA = {w0, w1}, wB = {w2, w3};
  edge_accum_pk(p0, p1, p2, vf2{q.a0, q.b0}, vf2{q.a1, q.b1},
                vf2{q.a2, q.b2}, wA, a0, a1, a2);
  edge_accum_pk(p0, p1, p2, vf2{q.c0, q.d0}, vf2{q.c1, q.d1},
                vf2{q.c2, q.d2}, wB, a0, a1, a2);
  wsv += wA + wB;
}

// Wave per node; lane = k*16+c; rows padded to 16 -> no guards.
// Software pipeline: e prefetched 2 iters ahead, q gathered 1 iter ahead.
// Over-reads land in the zeroed +64-entry pair slack; every pair entry
// (incl. pads/slack) holds rcv*48 in [0,48N) so speculative gathers are
// always in-bounds; their w is never accumulated.
__global__ __launch_bounds__(256, 8) void flowp_kernel(
    const float* __restrict__ xin, const int* __restrict__ row_start,
    const long long* __restrict__ pair, const float* __restrict__ tsq,
    const float* __restrict__ dsq, float* __restrict__ xout, int N) {
  int node = blockIdx.x * 4 + (threadIdx.x >> 6);
  if (node >= N) return;
  int lane = threadIdx.x & 63;
  int c = lane & 15;
  int k = lane >> 4;
  int c3 = c * 3;
  int beg = row_start[node];
  int end = row_start[node + 1];
  int ip = node * 48 + c3;
  float ps0 = xin[ip], ps1 = xin[ip + 1], ps2 = xin[ip + 2];
  vf2 p0 = {ps0, ps0}, p1 = {ps1, ps1}, p2 = {ps2, ps2};
  vf2 a0 = {0.f, 0.f}, a1 = {0.f, 0.f}, a2 = {0.f, 0.f}, wsv = {0.f, 0.f};
  int iters = (end - beg) >> 4;  // exact (rows padded to 16)
  if (iters > 0) {
    int j = beg + k;
    EQ ecur = load_e(pair, j);
    EQ enext = load_e(pair, j + 16);   // slack-covered over-read ok
    Q4 qcur = load_q(xin, ecur, c3);
    #pragma unroll 2
    for (int t = 0; t < iters; ++t) {
      EQ enn = load_e(pair, j + 32);   // e for t+2 (slack-covered)
      Q4 qnext = load_q(xin, enext, c3);  // q for t+1 (always safe)
      compute_iter(ecur, qcur, p0, p1, p2, a0, a1, a2, wsv);
      ecur = enext; enext = enn; qcur = qnext;
      j += 16;
    }
  }
  float A0 = a0.x + a0.y, A1 = a1.x + a1.y, A2 = a2.x + a2.y;
  float ws = wsv.x + wsv.y;
  A0 += __shfl_xor(A0, 16); A1 += __shfl_xor(A1, 16);
  A2 += __shfl_xor(A2, 16); ws += __shfl_xor(ws, 16);
  A0 += __shfl_xor(A0, 32); A1 += __shfl_xor(A1, 32);
  A2 += __shfl_xor(A2, 32); ws += __shfl_xor(ws, 32);
  if (k == 0) {
    float y0, y1, y2;
    node_step(A0, A1, A2, ws, ps0, ps1, ps2, tsq[c], dsq[c], y0, y1, y2);
    xout[ip] = y0; xout[ip + 1] = y1; xout[ip + 2] = y2;
  }
}

static inline size_t al16(size_t x) { return (x + 15) & ~(size_t)15; }

extern "C" void kernel_launch(void* const* d_in, const int* in_sizes, int n_in,
                              void* d_out, int out_size, void* d_ws, size_t ws_size,
                              hipStream_t stream) {
  const float* nodes = (const float*)d_in[0];  // [N,16,3]
  const float* ew    = (const float*)d_in[1];  // [E]
  const float* tsq   = (const float*)d_in[2];  // [16]
  const float* dsq   = (const float*)d_in[3];  // [16]
  const int*   snd   = (const int*)d_in[4];    // [E]
  const int*   rcv   = (const int*)d_in[5];    // [E]
  float* out = (float*)d_out;

  int E = in_sizes[1];
  int N = in_sizes[0] / 48;

  int NS = (N + (1 << SR_BITS) - 1) >> SR_BITS;  // node subranges (4)
  int NC = (E + (1 << CH_BITS) - 1) >> CH_BITS;  // edge chunks (49)

  // workspace (~34MB): row_start[N+4] | aux | pair[E+15N+64] | partial2(uchar)
  //                    | boffL (uchar, region kept at int size so xtmp alias
  //                    still fits: 9.8MB >= 9.6MB) | pos[E bytes]
  size_t padN  = (size_t)E + 15 * (size_t)N + 64;  // >= padded total + slack
  size_t rsB   = al16((size_t)(N + 4) * 4);
  size_t auxB  = 512;
  size_t pairB = al16(padN * 8);
  size_t p2B   = al16((size_t)NS * NC << SR_BITS);  // uchar
  size_t boffB = al16((size_t)NC * N * 4);          // sized as int for alias

  char* base = (char*)d_ws;
  int*           row_start = (int*)base;
  int*           btot      = (int*)(base + rsB);
  long long*     pair      = (long long*)(base + rsB + auxB);
  unsigned char* partial2  = (unsigned char*)(base + rsB + auxB + pairB);
  unsigned char* boffL     = (unsigned char*)(base + rsB + auxB + pairB + p2B);
  unsigned char* pos       = (unsigned char*)(base + rsB + auxB + pairB + p2B + boffB);
  float*         xtmp      = (float*)boffL;  // aliased; dead after fill

  int E4  = E >> 2;
  int nb  = (N + 1023) / 1024;   // tiles (<=64 required; 49 @ N=50K)
  int nb2 = (N + 255) / 256;
  int fbk = (E4 + 511) / 512;
  int nfb = (N + 3) / 4;

  hipMemsetAsync(pair, 0, pairB, stream);  // zero pad slots (w=0, rcv=0)
  lhist_kernel<<<dim3(NC, NS), 256, 0, stream>>>(snd, pos, partial2, E, NC);
  scan1A_kernel<<<nb, 1024, 0, stream>>>(partial2, boffL, row_start, btot, N, NC);
  scanCD_kernel<<<nb2, 256, 0, stream>>>(row_start, btot, N, nb);
  fill_kernel<<<fbk, 256, 0, stream>>>((const vi4*)snd, (const vi4*)rcv,
                                       (const vf4*)ew, pos, boffL, row_start,
                                       pair, snd, rcv, ew, N, E);

  // step 1: nodes -> xtmp ; step 2: xtmp -> out (not in-place: reads neighbors)
  flowp_kernel<<<nfb, 256, 0, stream>>>(nodes, row_start, pair, tsq, dsq, xtmp, N);
  flowp_kernel<<<nfb, 256, 0, stream>>>(xtmp, row_start, pair, tsq, dsq, out, N);
}

// Round 2
// 275.447 us; speedup vs baseline: 1.4983x; 1.4983x over previous
//
#include <hip/hip_runtime.h>
#include <math.h>

// FlowLayer: 2 steps of manifold (S^2) graph heat flow.
// N=50000 nodes, C=16 channels, D=3, E=1.6M edges.
//
// R19 = R18 build (kept: boffL uchar, scanCD fold -> residual 168->137us)
//       + flowp pipeline REDONE scalar-only.
// R18 post-mortem: EQ/Q4 structs passed by const& defeated SROA ->
// alloca promoted to LDS (8KB/block, 6.8M bank conflicts) + scratch
// spills (WRITE_SIZE 9.7->154MB); launch_bounds(256,8) capped VGPR at 64
// forcing more spills. flowp 59->137us.
// R19 pipeline rules: no aggregates, 24 named scalars, w extracted from
// e[t+1] at gather time (e[t] highs never live into compute), cap (256,6)
// (~85 VGPR, 6 waves/SIMD ~= R17's occupancy).
//
// NOTE: |u|^2 MUST be computed from u's components (not 1-cs^2): near
// antipodal pairs 1-cs^2 cancels catastrophically -> rsq explodes (R5 bug).

constexpr float EPS64F = 2.2204460492503131e-16f;  // np.float64 eps
constexpr float PI_F   = 3.14159265358979323846f;
constexpr int   SR_BITS = 14;                 // 16384-node subranges (64KB LDS)
constexpr int   CH_BITS = 15;                 // 32768-edge chunks

typedef int   vi4 __attribute__((ext_vector_type(4)));
typedef float vf4 __attribute__((ext_vector_type(4)));
typedef float vf2 __attribute__((ext_vector_type(2)));

// ---------------- CSR build ----------------

// LDS histogram: block (c = blockIdx.x, s = blockIdx.y).
__global__ __launch_bounds__(256) void lhist_kernel(
    const int* __restrict__ snd, unsigned char* __restrict__ pos,
    unsigned char* __restrict__ partial2, int E, int NC) {
  __shared__ int h[1 << SR_BITS];
  int tid = threadIdx.x;
  int c = blockIdx.x, s = blockIdx.y;
  for (int i = tid; i < (1 << SR_BITS); i += 256) h[i] = 0;
  __syncthreads();
  int base = c << CH_BITS;
  int cnt = min(1 << CH_BITS, E - base);
  int s0 = s << SR_BITS;
  const vi4* snd4 = (const vi4*)(snd + base);  // base is 32768-aligned
  int cnt4 = cnt >> 2;
  for (int i = tid; i < cnt4; i += 256) {
    vi4 sv = snd4[i];
    int e = base + (i << 2);
    int v;
    v = sv.x - s0; if ((unsigned)v < (1u << SR_BITS)) pos[e]     = (unsigned char)atomicAdd(&h[v], 1);
    v = sv.y - s0; if ((unsigned)v < (1u << SR_BITS)) pos[e + 1] = (unsigned char)atomicAdd(&h[v], 1);
    v = sv.z - s0; if ((unsigned)v < (1u << SR_BITS)) pos[e + 2] = (unsigned char)atomicAdd(&h[v], 1);
    v = sv.w - s0; if ((unsigned)v < (1u << SR_BITS)) pos[e + 3] = (unsigned char)atomicAdd(&h[v], 1);
  }
  if (tid == 0) {  // chunk tail (cnt % 4)
    for (int i = cnt4 << 2; i < cnt; ++i) {
      int v = snd[base + i] - s0;
      if ((unsigned)v < (1u << SR_BITS))
        pos[base + i] = (unsigned char)atomicAdd(&h[v], 1);
    }
  }
  __syncthreads();
  unsigned char* dst = partial2 + ((size_t)(s * NC + c) << SR_BITS);
  for (int i = tid; i < (1 << SR_BITS); i += 256)
    dst[i] = (unsigned char)h[i];
}

// Fused scan1+scanA with row padding: per-node exclusive fold over chunks
// (boffL in place, unpadded, uchar) -> degree; tile shfl-scan of PADDED
// degree (round up to 16) -> tile-local exclusive row_start + tile totals.
__global__ __launch_bounds__(1024) void scan1A_kernel(
    const unsigned char* __restrict__ partial2, unsigned char* __restrict__ boffL,
    int* __restrict__ row_start, int* __restrict__ btot, int N, int NC) {
  __shared__ int wsum[16];
  int tid = threadIdx.x;
  int lane = tid & 63, wave = tid >> 6;
  int i = blockIdx.x * 1024 + tid;
  int vpad = 0;
  if (i < N) {
    int s = i >> SR_BITS, lv = i & ((1 << SR_BITS) - 1);
    int run = 0;
    for (int c = 0; c < NC; ++c) {
      int t = partial2[((size_t)(s * NC + c) << SR_BITS) + lv];
      boffL[(size_t)c * N + i] = (unsigned char)run;  // run <= degree <= ~80
      run += t;
    }
    vpad = (run + 15) & ~15;  // padded degree
  }
  int incl = vpad;
  #pragma unroll
  for (int off = 1; off < 64; off <<= 1) {
    int t = __shfl_up(incl, off, 64);
    if (lane >= off) incl += t;
  }
  if (lane == 63) wsum[wave] = incl;
  __syncthreads();
  if (wave == 0 && lane < 16) {
    int wincl = wsum[lane];
    #pragma unroll
    for (int off = 1; off < 16; off <<= 1) {
      int t = __shfl_up(wincl, off, 64);
      if (lane >= off) wincl += t;
    }
    wsum[lane] = wincl;
  }
  __syncthreads();
  int woff = (wave > 0) ? wsum[wave - 1] : 0;
  if (i < N) row_start[i] = woff + incl - vpad;  // tile-local exclusive
  if (tid == 0) btot[blockIdx.x] = wsum[15];
}

// scanCD (+ folded scanB): each block wave-scans the <=64 tile totals in
// LDS, then finalizes row_start only (fill adds rs via gather itself).
__global__ __launch_bounds__(256) void scanCD_kernel(
    int* __restrict__ row_start, const int* __restrict__ btot, int N, int nb) {
  __shared__ int bsh[64];
  int tid = threadIdx.x;
  if (tid < 64) {
    int v = (tid < nb) ? btot[tid] : 0;
    int incl = v;
    #pragma unroll
    for (int off = 1; off < 64; off <<= 1) {
      int t = __shfl_up(incl, off, 64);
      if (tid >= off) incl += t;
    }
    bsh[tid] = incl - v;  // exclusive tile offset
    if (blockIdx.x == 0 && tid == 63) row_start[N] = incl;  // padded total
  }
  __syncthreads();
  int i = blockIdx.x * 256 + tid;
  if (i >= N) return;
  row_start[i] = row_start[i] + bsh[i >> 10];
}

// Atomic-free fill: slot = row_start[snd] + boffL[chunk][snd] + pos[e];
// packs (w, rcv*48). Pad slots (row tails) stay zero from the memset.
// row_start (200KB) and the chunk's boffL slice (50KB) are L2-resident.
__global__ __launch_bounds__(256) void fill_kernel(
    const vi4* __restrict__ snd4, const vi4* __restrict__ rcv4,
    const vf4* __restrict__ ew4, const unsigned char* __restrict__ pos,
    const unsigned char* __restrict__ boffL, const int* __restrict__ row_start,
    long long* __restrict__ pair,
    const int* __restrict__ snd, const int* __restrict__ rcv,
    const float* __restrict__ ew, int N, int E) {
  int tid = threadIdx.x;
  int E4 = E >> 2;
  #pragma unroll
  for (int gg = 0; gg < 2; ++gg) {
    int g = blockIdx.x * 512 + gg * 256 + tid;
    if (g < E4) {
      int e = g << 2;
      const unsigned char* bc = boffL + (size_t)(e >> CH_BITS) * N;  // same chunk e..e+3
      vi4 s = __builtin_nontemporal_load(&snd4[g]);
      vi4 r = __builtin_nontemporal_load(&rcv4[g]);
      vf4 w = __builtin_nontemporal_load(&ew4[g]);
      unsigned pb = *(const unsigned*)(pos + e);
      int rs0 = row_start[s.x] + bc[s.x];
      int rs1 = row_start[s.y] + bc[s.y];
      int rs2 = row_start[s.z] + bc[s.z];
      int rs3 = row_start[s.w] + bc[s.w];
      pair[rs0 + (pb & 255u)] =
          (long long)(((unsigned long long)(unsigned)__float_as_int(w.x) << 32) | (unsigned)(r.x * 48));
      pair[rs1 + ((pb >> 8) & 255u)] =
          (long long)(((unsigned long long)(unsigned)__float_as_int(w.y) << 32) | (unsigned)(r.y * 48));
      pair[rs2 + ((pb >> 16) & 255u)] =
          (long long)(((unsigned long long)(unsigned)__float_as_int(w.z) << 32) | (unsigned)(r.z * 48));
      pair[rs3 + (pb >> 24)] =
          (long long)(((unsigned long long)(unsigned)__float_as_int(w.w) << 32) | (unsigned)(r.w * 48));
    }
  }
  if (blockIdx.x == 0 && tid == 0) {
    for (int e = E4 << 2; e < E; ++e) {  // edge tail
      int sn = snd[e];
      pair[row_start[sn] + boffL[(size_t)(e >> CH_BITS) * N + sn] + pos[e]] =
          (long long)(((unsigned long long)(unsigned)__float_as_int(ew[e]) << 32) | (unsigned)(rcv[e] * 48));
    }
  }
}

// ---------------- flow (R10 flowp math, scalar-only pipeline) ----------------

__device__ __forceinline__ void edge_accum_pk(
    vf2 p0, vf2 p1, vf2 p2, vf2 q0, vf2 q1, vf2 q2, vf2 w,
    vf2& a0, vf2& a1, vf2& a2) {
  vf2 cs = p0 * q0 + p1 * q1 + p2 * q2;
  cs = __builtin_elementwise_min(vf2{1.f, 1.f},
       __builtin_elementwise_max(vf2{-1.f, -1.f}, cs));
  vf2 u0 = q0 - cs * p0;
  vf2 u1 = q1 - cs * p1;
  vf2 u2 = q2 - cs * p2;
  // |u|^2 from components (R5 lesson)
  vf2 un2 = __builtin_elementwise_max(u0 * u0 + u1 * u1 + u2 * u2,
                                      vf2{1e-24f, 1e-24f});
  // acos via A&S 4.4.45 (|err| <= 6.7e-5; output threshold is 2e-2)
  vf2 ax = __builtin_elementwise_abs(cs);
  vf2 s = __builtin_elementwise_sqrt(vf2{1.f, 1.f} - ax);
  vf2 poly = ((ax * -0.0187293f + 0.0742610f) * ax - 0.2121144f) * ax
             + 1.5707288f;
  vf2 th = s * poly;
  vf2 theta;
  theta.x = (cs.x >= 0.0f) ? th.x : (PI_F - th.x);
  theta.y = (cs.y >= 0.0f) ? th.y : (PI_F - th.y);
  vf2 rsq;
  rsq.x = __builtin_amdgcn_rsqf(un2.x);
  rsq.y = __builtin_amdgcn_rsqf(un2.y);
  vf2 coef = w * theta * rsq;
  a0 += coef * u0;
  a1 += coef * u1;
  a2 += coef * u2;
}

__device__ __forceinline__ void node_step(
    float a0, float a1, float a2, float ws, float p0, float p1, float p2,
    float ts, float dsv, float& y0, float& y1, float& y2) {
  // v_lap = -agg/deg; nrm/scale sign-invariant; -(v_lap*scale)*t = +g*scale*t
  float invdg = __builtin_amdgcn_rcpf(ws + 1e-12f);
  float g0 = a0 * invdg, g1 = a1 * invdg, g2 = a2 * invdg;
  float nrm = sqrtf(fmaf(g0, g0, fmaf(g1, g1, g2 * g2)) + EPS64F);
  float tch = ts * ts * 0.5f;  // t_sqrt^2 / N_STEPS
  float dch = dsv * dsv;
  float alp = __builtin_amdgcn_rcpf(1.0f + __expf(dch - nrm));  // sigmoid
  float scale = (nrm * alp <= 1.0f) ? alp : __builtin_amdgcn_rcpf(nrm);
  float f = scale * tch;
  float v0 = g0 * f, v1 = g1 * f, v2 = g2 * f;
  float nv = sqrtf(fmaf(v0, v0, fmaf(v1, v1, v2 * v2)));
  float cn = __cosf(nv);
  float sc = (nv > 1e-20f) ? (__sinf(nv) * __builtin_amdgcn_rcpf(nv)) : 1.0f;
  float t0 = fmaf(cn, p0, sc * v0);
  float t1 = fmaf(cn, p1, sc * v1);
  float t2 = fmaf(cn, p2, sc * v2);
  float inv = __builtin_amdgcn_rsqf(fmaf(t0, t0, fmaf(t1, t1, t2 * t2)));
  y0 = t0 * inv; y1 = t1 * inv; y2 = t2 * inv;
}

// Wave per node; lane = k*16+c; rows padded to 16 -> no guards.
// Software pipeline, SCALAR-ONLY state (R18 lesson: no structs/refs):
//   w[t],q[t] in regs -> compute t ; e[t+1] gathered -> w/q[t+1] ;
//   e[t+2] in flight. Over-reads land in the zeroed +64-entry pair slack;
//   every pair entry (incl. pads/slack) holds rcv*48 in [0,48N) so
//   speculative gathers are always in-bounds; their w is never accumulated.
__global__ __launch_bounds__(256, 6) void flowp_kernel(
    const float* __restrict__ xin, const int* __restrict__ row_start,
    const long long* __restrict__ pair, const float* __restrict__ tsq,
    const float* __restrict__ dsq, float* __restrict__ xout, int N) {
  int node = blockIdx.x * 4 + (threadIdx.x >> 6);
  if (node >= N) return;
  int lane = threadIdx.x & 63;
  int c = lane & 15;
  int k = lane >> 4;
  int c3 = c * 3;
  int beg = row_start[node];
  int end = row_start[node + 1];
  int ip = node * 48 + c3;
  float ps0 = xin[ip], ps1 = xin[ip + 1], ps2 = xin[ip + 2];
  vf2 p0 = {ps0, ps0}, p1 = {ps1, ps1}, p2 = {ps2, ps2};
  vf2 a0 = {0.f, 0.f}, a1 = {0.f, 0.f}, a2 = {0.f, 0.f}, wsv = {0.f, 0.f};
  int iters = (end - beg) >> 4;  // exact (rows padded to 16)
  if (iters > 0) {
    int j = beg + k;
    // e[0]
    long long t0 = __builtin_nontemporal_load(&pair[j]);
    long long t1 = __builtin_nontemporal_load(&pair[j + 4]);
    long long t2 = __builtin_nontemporal_load(&pair[j + 8]);
    long long t3 = __builtin_nontemporal_load(&pair[j + 12]);
    // e[1] (next row or slack if iters==1 -- valid entries either way)
    long long eb0 = __builtin_nontemporal_load(&pair[j + 16]);
    long long eb1 = __builtin_nontemporal_load(&pair[j + 20]);
    long long eb2 = __builtin_nontemporal_load(&pair[j + 24]);
    long long eb3 = __builtin_nontemporal_load(&pair[j + 28]);
    // w[0] + q[0]
    float w0 = __int_as_float((int)(t0 >> 32));
    float w1 = __int_as_float((int)(t1 >> 32));
    float w2 = __int_as_float((int)(t2 >> 32));
    float w3 = __int_as_float((int)(t3 >> 32));
    const float* qp;
    qp = xin + ((int)t0 + c3); float qa0 = qp[0], qa1 = qp[1], qa2 = qp[2];
    qp = xin + ((int)t1 + c3); float qb0 = qp[0], qb1 = qp[1], qb2 = qp[2];
    qp = xin + ((int)t2 + c3); float qc0 = qp[0], qc1 = qp[1], qc2 = qp[2];
    qp = xin + ((int)t3 + c3); float qd0 = qp[0], qd1 = qp[1], qd2 = qp[2];
    #pragma unroll 2
    for (int t = 0; t < iters; ++t, j += 16) {
      // e[t+2] (slack-covered over-read)
      long long ec0 = __builtin_nontemporal_load(&pair[j + 32]);
      long long ec1 = __builtin_nontemporal_load(&pair[j + 36]);
      long long ec2 = __builtin_nontemporal_load(&pair[j + 40]);
      long long ec3 = __builtin_nontemporal_load(&pair[j + 44]);
      // w[t+1] + q[t+1] from e[t+1] (eb dies here)
      float nw0 = __int_as_float((int)(eb0 >> 32));
      float nw1 = __int_as_float((int)(eb1 >> 32));
      float nw2 = __int_as_float((int)(eb2 >> 32));
      float nw3 = __int_as_float((int)(eb3 >> 32));
      const float* np;
      np = xin + ((int)eb0 + c3); float na0 = np[0], na1 = np[1], na2 = np[2];
      np = xin + ((int)eb1 + c3); float nb0 = np[0], nb1 = np[1], nb2 = np[2];
      np = xin + ((int)eb2 + c3); float nc0 = np[0], nc1 = np[1], nc2 = np[2];
      np = xin + ((int)eb3 + c3); float nd0 = np[0], nd1 = np[1], nd2 = np[2];
      // compute iter t
      vf2 wA = {w0, w1}, wB = {w2, w3};
      edge_accum_pk(p0, p1, p2, vf2{qa0, qb0}, vf2{qa1, qb1},
                    vf2{qa2, qb2}, wA, a0, a1, a2);
      edge_accum_pk(p0, p1, p2, vf2{qc0, qd0}, vf2{qc1, qd1},
                    vf2{qc2, qd2}, wB, a0, a1, a2);
      wsv += wA + wB;
      // rotate (pure register renames under unroll 2)
      w0 = nw0; w1 = nw1; w2 = nw2; w3 = nw3;
      qa0 = na0; qa1 = na1; qa2 = na2;
      qb0 = nb0; qb1 = nb1; qb2 = nb2;
      qc0 = nc0; qc1 = nc1; qc2 = nc2;
      qd0 = nd0; qd1 = nd1; qd2 = nd2;
      eb0 = ec0; eb1 = ec1; eb2 = ec2; eb3 = ec3;
    }
  }
  float A0 = a0.x + a0.y, A1 = a1.x + a1.y, A2 = a2.x + a2.y;
  float ws = wsv.x + wsv.y;
  A0 += __shfl_xor(A0, 16); A1 += __shfl_xor(A1, 16);
  A2 += __shfl_xor(A2, 16); ws += __shfl_xor(ws, 16);
  A0 += __shfl_xor(A0, 32); A1 += __shfl_xor(A1, 32);
  A2 += __shfl_xor(A2, 32); ws += __shfl_xor(ws, 32);
  if (k == 0) {
    float y0, y1, y2;
    node_step(A0, A1, A2, ws, ps0, ps1, ps2, tsq[c], dsq[c], y0, y1, y2);
    xout[ip] = y0; xout[ip + 1] = y1; xout[ip + 2] = y2;
  }
}

static inline size_t al16(size_t x) { return (x + 15) & ~(size_t)15; }

extern "C" void kernel_launch(void* const* d_in, const int* in_sizes, int n_in,
                              void* d_out, int out_size, void* d_ws, size_t ws_size,
                              hipStream_t stream) {
  const float* nodes = (const float*)d_in[0];  // [N,16,3]
  const float* ew    = (const float*)d_in[1];  // [E]
  const float* tsq   = (const float*)d_in[2];  // [16]
  const float* dsq   = (const float*)d_in[3];  // [16]
  const int*   snd   = (const int*)d_in[4];    // [E]
  const int*   rcv   = (const int*)d_in[5];    // [E]
  float* out = (float*)d_out;

  int E = in_sizes[1];
  int N = in_sizes[0] / 48;

  int NS = (N + (1 << SR_BITS) - 1) >> SR_BITS;  // node subranges (4)
  int NC = (E + (1 << CH_BITS) - 1) >> CH_BITS;  // edge chunks (49)

  // workspace (~34MB): row_start[N+4] | aux | pair[E+15N+64] | partial2(uchar)
  //                    | boffL (uchar, region kept at int size so xtmp alias
  //                    still fits: 9.8MB >= 9.6MB) | pos[E bytes]
  size_t padN  = (size_t)E + 15 * (size_t)N + 64;  // >= padded total + slack
  size_t rsB   = al16((size_t)(N + 4) * 4);
  size_t auxB  = 512;
  size_t pairB = al16(padN * 8);
  size_t p2B   = al16((size_t)NS * NC << SR_BITS);  // uchar
  size_t boffB = al16((size_t)NC * N * 4);          // sized as int for alias

  char* base = (char*)d_ws;
  int*           row_start = (int*)base;
  int*           btot      = (int*)(base + rsB);
  long long*     pair      = (long long*)(base + rsB + auxB);
  unsigned char* partial2  = (unsigned char*)(base + rsB + auxB + pairB);
  unsigned char* boffL     = (unsigned char*)(base + rsB + auxB + pairB + p2B);
  unsigned char* pos       = (unsigned char*)(base + rsB + auxB + pairB + p2B + boffB);
  float*         xtmp      = (float*)boffL;  // aliased; dead after fill

  int E4  = E >> 2;
  int nb  = (N + 1023) / 1024;   // tiles (<=64 required; 49 @ N=50K)
  int nb2 = (N + 255) / 256;
  int fbk = (E4 + 511) / 512;
  int nfb = (N + 3) / 4;

  hipMemsetAsync(pair, 0, pairB, stream);  // zero pad slots (w=0, rcv=0)
  lhist_kernel<<<dim3(NC, NS), 256, 0, stream>>>(snd, pos, partial2, E, NC);
  scan1A_kernel<<<nb, 1024, 0, stream>>>(partial2, boffL, row_start, btot, N, NC);
  scanCD_kernel<<<nb2, 256, 0, stream>>>(row_start, btot, N, nb);
  fill_kernel<<<fbk, 256, 0, stream>>>((const vi4*)snd, (const vi4*)rcv,
                                       (const vf4*)ew, pos, boffL, row_start,
                                       pair, snd, rcv, ew, N, E);

  // step 1: nodes -> xtmp ; step 2: xtmp -> out (not in-place: reads neighbors)
  flowp_kernel<<<nfb, 256, 0, stream>>>(nodes, row_start, pair, tsq, dsq, xtmp, N);
  flowp_kernel<<<nfb, 256, 0, stream>>>(xtmp, row_start, pair, tsq, dsq, out, N);
}